// Round 14
// baseline (299.809 us; speedup 1.0000x reference)
//
#include <hip/hip_runtime.h>
#include <hip/hip_bf16.h>
#include <math.h>

#define DMODEL  1024
#define DINNER  2048
#define DSTATE  16
#define DCONV   4
#define DTRANK  64
#define NH      8
#define PH      256
#define TOTOUT  4416
#define NTOT2   6528            // [Z 2048 | U 2048 | RES 2048 | DBC 320+64pad] = 51*128
#define MB_ROWS 4096            // rows per batch
#define LC      64              // scan chunk length
#define NCB     (MB_ROWS/LC)    // 64 chunks per batch

typedef __attribute__((ext_vector_type(8))) short bf16x8;
typedef __attribute__((ext_vector_type(4))) float f32x4;

__device__ inline unsigned cvt2bf(float lo, float hi) {
    unsigned r;
    asm("v_cvt_pk_bf16_f32 %0, %1, %2" : "=v"(r) : "v"(lo), "v"(hi));
    return r;
}
__device__ inline ushort f2bf(float v) { return (ushort)(cvt2bf(v, v) & 0xffffu); }
__device__ inline float bf2f(ushort u) {
    union { unsigned u; float f; } w; w.u = (unsigned)u << 16; return w.f;
}
__device__ inline void gload16(const ushort* g, ushort* l) {
    __builtin_amdgcn_global_load_lds((const __attribute__((address_space(1))) unsigned*)(const void*)g,
                                     (__attribute__((address_space(3))) unsigned*)(void*)l, 16, 0, 0);
}

// ---------------- fused convert: Wcat repack [Wz|Wu|Wres|Wbc|pad] + (W_out*norm_w) + x ----------------
__global__ __launch_bounds__(256) void cvt_all(const float* __restrict__ W_in,
                                               const float* __restrict__ W_res,
                                               const float* __restrict__ W_out,
                                               const float* __restrict__ norm_w,
                                               const float* __restrict__ x,
                                               ushort* __restrict__ WB,
                                               ushort* __restrict__ XBF) {
    const size_t E_WCAT = (size_t)NTOT2 * DMODEL;
    const size_t E_WOUT = E_WCAT + (size_t)DMODEL * DINNER;
    size_t i = ((size_t)blockIdx.x * 256 + threadIdx.x) * 8;
    const float* src;
    ushort* dst;
    bool zero = false, scale = false;
    size_t k0 = 0;
    if (i < E_WCAT) {
        size_t r = i >> 10, c = i & 1023;
        if (r < 4096)       src = W_in + (r << 10) + c;           // z,u rows
        else if (r < 6144)  src = W_res + ((r - 4096) << 10) + c; // res rows
        else if (r < 6464)  src = W_in + ((r - 2048) << 10) + c;  // dbc rows 4096..4415
        else { src = W_in; zero = true; }                          // pad rows
        dst = WB + i;
    } else if (i < E_WOUT) {
        size_t o = i - E_WCAT;
        src = W_out + o;
        dst = WB + i;
        scale = true;
        k0 = o & (DINNER - 1);
    } else {
        src = x + (i - E_WOUT);
        dst = XBF + (i - E_WOUT);
    }
    float4 v0, v1;
    if (zero) { v0 = make_float4(0.f, 0.f, 0.f, 0.f); v1 = v0; }
    else { v0 = *(const float4*)src; v1 = *(const float4*)(src + 4); }
    if (scale) {   // fold norm_w into W_out
        float4 n0 = *(const float4*)(norm_w + k0);
        float4 n1 = *(const float4*)(norm_w + k0 + 4);
        v0.x *= n0.x; v0.y *= n0.y; v0.z *= n0.z; v0.w *= n0.w;
        v1.x *= n1.x; v1.y *= n1.y; v1.z *= n1.z; v1.w *= n1.w;
    }
    uint4 o;
    o.x = cvt2bf(v0.x, v0.y); o.y = cvt2bf(v0.z, v0.w);
    o.z = cvt2bf(v1.x, v1.y); o.w = cvt2bf(v1.z, v1.w);
    *(uint4*)dst = o;
}

// ========== fused GEMM: 256x128 tile, tri-buffer, counted vmcnt(3) (proven) ==========
__global__ __launch_bounds__(512) void gemm_fused(const ushort* __restrict__ A,
                                                  const ushort* __restrict__ W,
                                                  ushort* __restrict__ Zb,
                                                  ushort* __restrict__ Ub,
                                                  ushort* __restrict__ RESb,
                                                  float* __restrict__ DBCp,
                                                  int ntx, int K) {
    __shared__ __align__(16) ushort L[3 * 12288];
    const int nwg  = gridDim.x;
    const int orig = blockIdx.x;
    const int swz  = (orig & 7) * (nwg >> 3) + (orig >> 3);   // bijective: nwg % 8 == 0
    const int bx = swz % ntx, by = swz / ntx;
    const int row0 = by * 256, col0 = bx * 128;

    const int t    = threadIdx.x;
    const int lane = t & 63, w = t >> 6;
    const int wr   = w >> 1, wc = w & 1;
    const int l15  = lane & 15, l4 = lane >> 4;

    const int r0g = t >> 2, s0g = t & 3;
    const int r1g = r0g + 128;
    const int rr0 = r0g ^ ((r0g >> 3) & 1), cc0 = s0g ^ ((r0g >> 1) & 3);
    const int rr1 = r1g ^ ((r1g >> 3) & 1), cc1 = s0g ^ ((r1g >> 1) & 3);
    const ushort* sA0 = A + (size_t)(row0 + rr0) * K + cc0 * 8;
    const ushort* sA1 = A + (size_t)(row0 + rr1) * K + cc1 * 8;
    const ushort* sB0 = W + (size_t)(col0 + rr0) * K + cc0 * 8;

    int offA[4], offB[4];
    #pragma unroll
    for (int mi = 0; mi < 4; mi++) {
        int rq = wr * 64 + mi * 16 + l15;
        offA[mi] = (rq * 32 + l4 * 8) ^ (((rq >> 1) & 7) << 3);
    }
    #pragma unroll
    for (int ni = 0; ni < 4; ni++) {
        int rq = wc * 64 + ni * 16 + l15;
        offB[ni] = 8192 + ((rq * 32 + l4 * 8) ^ (((rq >> 1) & 7) << 3));
    }

    f32x4 acc[4][4];
    #pragma unroll
    for (int i = 0; i < 4; i++)
        #pragma unroll
        for (int j = 0; j < 4; j++)
            acc[i][j] = (f32x4){0.f, 0.f, 0.f, 0.f};

    const int KT = K >> 5;
    gload16(sA0,      &L[t * 8]);
    gload16(sA1,      &L[4096 + t * 8]);
    gload16(sB0,      &L[8192 + t * 8]);
    gload16(sA0 + 32, &L[12288 + t * 8]);
    gload16(sA1 + 32, &L[12288 + 4096 + t * 8]);
    gload16(sB0 + 32, &L[12288 + 8192 + t * 8]);
    asm volatile("s_waitcnt vmcnt(3)" ::: "memory");
    __builtin_amdgcn_sched_barrier(0);
    __builtin_amdgcn_s_barrier();
    __builtin_amdgcn_sched_barrier(0);

    for (int kt = 0; kt < KT; ++kt) {
        const bool pre = (kt + 2) < KT;
        if (pre) {
            ushort* bp2 = &L[((kt + 2) % 3) * 12288];
            const int ko = (kt + 2) << 5;
            gload16(sA0 + ko, bp2 + t * 8);
            gload16(sA1 + ko, bp2 + 4096 + t * 8);
            gload16(sB0 + ko, bp2 + 8192 + t * 8);
        }
        const ushort* bp = &L[(kt % 3) * 12288];
        bf16x8 af[4], bw[4];
        #pragma unroll
        for (int mi = 0; mi < 4; mi++) af[mi] = *(const bf16x8*)(bp + offA[mi]);
        #pragma unroll
        for (int ni = 0; ni < 4; ni++) bw[ni] = *(const bf16x8*)(bp + offB[ni]);
        __builtin_amdgcn_s_setprio(1);
        #pragma unroll
        for (int mi = 0; mi < 4; mi++)
            #pragma unroll
            for (int ni = 0; ni < 4; ni++)
                acc[mi][ni] = __builtin_amdgcn_mfma_f32_16x16x32_bf16(af[mi], bw[ni], acc[mi][ni], 0, 0, 0);
        __builtin_amdgcn_s_setprio(0);
        if (pre) { asm volatile("s_waitcnt vmcnt(3)" ::: "memory"); }
        else     { asm volatile("s_waitcnt vmcnt(0)" ::: "memory"); }
        __builtin_amdgcn_sched_barrier(0);
        __builtin_amdgcn_s_barrier();
        __builtin_amdgcn_sched_barrier(0);
    }

    #pragma unroll
    for (int mi = 0; mi < 4; mi++) {
        #pragma unroll
        for (int ni = 0; ni < 4; ni++) {
            #pragma unroll
            for (int rr = 0; rr < 4; rr++) {
                const int row = row0 + wr * 64 + mi * 16 + l4 * 4 + rr;
                const int col = col0 + wc * 64 + ni * 16 + l15;
                const float v = acc[mi][ni][rr];
                if (col0 < DINNER) {
                    Zb[(size_t)row * DINNER + col] = f2bf(v);
                } else if (col0 < 2 * DINNER) {
                    Ub[(size_t)row * DINNER + (col - DINNER)] = f2bf(v);
                } else if (col0 < 3 * DINNER) {
                    RESb[(size_t)row * DINNER + (col - 2 * DINNER)] = f2bf(v);
                } else {
                    if (col < 3 * DINNER + 320)
                        DBCp[(size_t)row * 320 + (col - 3 * DINNER)] = v;
                }
            }
        }
    }
}

// ========== out-proj GEMM: 128x128, tri-buffer, vmcnt(4); epilogue applies per-row rms inv ==========
__global__ __launch_bounds__(256) void gemm_out128(const ushort* __restrict__ A,
                                                   const ushort* __restrict__ W,
                                                   const float* __restrict__ ssqp,
                                                   float* __restrict__ C0,
                                                   int ntx, int K, int ldc) {
    __shared__ __align__(16) ushort L[3 * 8192];
    const int nwg  = gridDim.x;
    const int orig = blockIdx.x;
    const int swz  = (orig & 7) * (nwg >> 3) + (orig >> 3);
    const int bx = swz % ntx, by = swz / ntx;
    const int row0 = by * 128, col0 = bx * 128;

    const int t    = threadIdx.x;
    const int lane = t & 63, w = t >> 6;
    const int wr   = w >> 1, wc = w & 1;
    const int l15  = lane & 15, l4 = lane >> 4;

    const int r0g = t >> 2, s0g = t & 3;
    const int r1g = r0g + 64;
    const int rr0 = r0g ^ ((r0g >> 3) & 1), cc0 = s0g ^ ((r0g >> 1) & 3);
    const int rr1 = r1g ^ ((r1g >> 3) & 1), cc1 = s0g ^ ((r1g >> 1) & 3);
    const ushort* sA0 = A + (size_t)(row0 + rr0) * K + cc0 * 8;
    const ushort* sA1 = A + (size_t)(row0 + rr1) * K + cc1 * 8;
    const ushort* sB0 = W + (size_t)(col0 + rr0) * K + cc0 * 8;
    const ushort* sB1 = W + (size_t)(col0 + rr1) * K + cc1 * 8;

    int offA[4], offB[4];
    #pragma unroll
    for (int mi = 0; mi < 4; mi++) {
        int rq = wr * 64 + mi * 16 + l15;
        offA[mi] = (rq * 32 + l4 * 8) ^ (((rq >> 1) & 7) << 3);
    }
    #pragma unroll
    for (int ni = 0; ni < 4; ni++) {
        int rq = wc * 64 + ni * 16 + l15;
        offB[ni] = 4096 + ((rq * 32 + l4 * 8) ^ (((rq >> 1) & 7) << 3));
    }

    f32x4 acc[4][4];
    #pragma unroll
    for (int i = 0; i < 4; i++)
        #pragma unroll
        for (int j = 0; j < 4; j++)
            acc[i][j] = (f32x4){0.f, 0.f, 0.f, 0.f};

    const int KT = K >> 5;
    gload16(sA0,      &L[t * 8]);
    gload16(sA1,      &L[2048 + t * 8]);
    gload16(sB0,      &L[4096 + t * 8]);
    gload16(sB1,      &L[6144 + t * 8]);
    gload16(sA0 + 32, &L[8192 + t * 8]);
    gload16(sA1 + 32, &L[8192 + 2048 + t * 8]);
    gload16(sB0 + 32, &L[8192 + 4096 + t * 8]);
    gload16(sB1 + 32, &L[8192 + 6144 + t * 8]);
    asm volatile("s_waitcnt vmcnt(4)" ::: "memory");
    __builtin_amdgcn_sched_barrier(0);
    __builtin_amdgcn_s_barrier();
    __builtin_amdgcn_sched_barrier(0);

    for (int kt = 0; kt < KT; ++kt) {
        const bool pre = (kt + 2) < KT;
        if (pre) {
            ushort* bp2 = &L[((kt + 2) % 3) * 8192];
            const int ko = (kt + 2) << 5;
            gload16(sA0 + ko, bp2 + t * 8);
            gload16(sA1 + ko, bp2 + 2048 + t * 8);
            gload16(sB0 + ko, bp2 + 4096 + t * 8);
            gload16(sB1 + ko, bp2 + 6144 + t * 8);
        }
        const ushort* bp = &L[(kt % 3) * 8192];
        bf16x8 af[4], bw[4];
        #pragma unroll
        for (int mi = 0; mi < 4; mi++) af[mi] = *(const bf16x8*)(bp + offA[mi]);
        #pragma unroll
        for (int ni = 0; ni < 4; ni++) bw[ni] = *(const bf16x8*)(bp + offB[ni]);
        __builtin_amdgcn_s_setprio(1);
        #pragma unroll
        for (int mi = 0; mi < 4; mi++)
            #pragma unroll
            for (int ni = 0; ni < 4; ni++)
                acc[mi][ni] = __builtin_amdgcn_mfma_f32_16x16x32_bf16(af[mi], bw[ni], acc[mi][ni], 0, 0, 0);
        __builtin_amdgcn_s_setprio(0);
        if (pre) { asm volatile("s_waitcnt vmcnt(4)" ::: "memory"); }
        else     { asm volatile("s_waitcnt vmcnt(0)" ::: "memory"); }
        __builtin_amdgcn_sched_barrier(0);
        __builtin_amdgcn_s_barrier();
        __builtin_amdgcn_sched_barrier(0);
    }

    float inv[4][4];
    #pragma unroll
    for (int mi = 0; mi < 4; mi++)
        #pragma unroll
        for (int rr = 0; rr < 4; rr++) {
            const int row = row0 + wr * 64 + mi * 16 + l4 * 4 + rr;
            const float* p = ssqp + (size_t)row * 8;
            float s = ((p[0] + p[1]) + (p[2] + p[3])) + ((p[4] + p[5]) + (p[6] + p[7]));
            inv[mi][rr] = rsqrtf(s * (1.f / (float)DINNER) + 1e-6f);
        }

    #pragma unroll
    for (int mi = 0; mi < 4; mi++)
        #pragma unroll
        for (int ni = 0; ni < 4; ni++)
            #pragma unroll
            for (int rr = 0; rr < 4; rr++) {
                const int row = row0 + wr * 64 + mi * 16 + l4 * 4 + rr;
                const int col = col0 + wc * 64 + ni * 16 + l15;
                C0[(size_t)row * ldc + col] = acc[mi][ni][rr] * inv[mi][rr];
            }
}

// ---------------- scan phase 1: 2 channels/thread, head-pair block ----------------
// grid (Mr/LC, NH/2), 256 threads. Waves 0-1 = head hp*2, waves 2-3 = head hp*2+1.
__global__ __launch_bounds__(256) void scan_local(const ushort* __restrict__ Ub,
                                                  const float* __restrict__ DBC,
                                                  const float* __restrict__ W_dt,
                                                  const float* __restrict__ dt_bias,
                                                  const float* __restrict__ A_log,
                                                  const float* __restrict__ cw,
                                                  const float* __restrict__ cb,
                                                  float* __restrict__ hloc,
                                                  float* __restrict__ Pc) {
    const int c = blockIdx.x, hp = blockIdx.y;
    const int pidx = threadIdx.x;
    const int hh = pidx >> 7;              // head within pair (wave-uniform)
    const int h  = hp * 2 + hh;
    const int li = pidx & 127;
    const int ch = h * PH + li * 2;        // first of 2 adjacent channels
    const int t0 = c * LC;
    __shared__ float sdt[2][LC];
    __shared__ float sdA[2][LC][DSTATE];
    __shared__ float sdB[2][LC][DSTATE];

    if (pidx < 128) {   // dt head: 2 heads x 64 rows
        const int hh2 = pidx >> 6, tt = pidx & 63;
        const int h2 = hp * 2 + hh2;
        const float* row = DBC + (size_t)(t0 + tt) * 320;
        const float* wd = W_dt + h2 * DTRANK;
        float acc = dt_bias[h2];
        #pragma unroll 16
        for (int r2 = 0; r2 < DTRANK; r2++) acc = fmaf(row[r2], wd[r2], acc);
        float sp = acc > 20.f ? acc : log1pf(expf(acc));
        sdt[hh2][tt] = fminf(fmaxf(sp, 1e-4f), 1.0f);
    }
    const float4 cwa = *(const float4*)(cw + ch * 4);
    const float4 cwb = *(const float4*)(cw + ch * 4 + 4);
    const float2 cbv = *(const float2*)(cb + ch);
    const int bs = (c / NCB) * MB_ROWS;
    float um3a = 0.f, um2a = 0.f, um1a = 0.f, um3b = 0.f, um2b = 0.f, um1b = 0.f;
    if (t0 - 3 >= bs) { ushort2 v = *(const ushort2*)(Ub + (size_t)(t0 - 3) * DINNER + ch); um3a = bf2f(v.x); um3b = bf2f(v.y); }
    if (t0 - 2 >= bs) { ushort2 v = *(const ushort2*)(Ub + (size_t)(t0 - 2) * DINNER + ch); um2a = bf2f(v.x); um2b = bf2f(v.y); }
    if (t0 - 1 >= bs) { ushort2 v = *(const ushort2*)(Ub + (size_t)(t0 - 1) * DINNER + ch); um1a = bf2f(v.x); um1b = bf2f(v.y); }
    __syncthreads();

    {   // coeff staging: 2 heads x 64 t x 16 n = 2048 entries, 8 per thread
        const int sn = li & 15, stt = li >> 4;           // stt 0-7
        const float nA = -expf(A_log[h * DSTATE + sn]);
        #pragma unroll
        for (int j = 0; j < 8; j++) {
            int tt = stt + j * 8;
            size_t trow = (size_t)(t0 + tt);
            float dv = sdt[hh][tt];
            sdA[hh][tt][sn] = expf(dv * nA);
            sdB[hh][tt][sn] = dv * DBC[trow * 320 + 64 + h * DSTATE + sn];
        }
    }
    __syncthreads();

    float ha[DSTATE] = {}, hb[DSTATE] = {};
    for (int t = 0; t < LC; t++) {
        ushort2 uv = *(const ushort2*)(Ub + (size_t)(t0 + t) * DINNER + ch);
        float u0a = bf2f(uv.x), u0b = bf2f(uv.y);
        float upa = fmaf(cwa.w, u0a, fmaf(cwa.z, um1a, fmaf(cwa.y, um2a, fmaf(cwa.x, um3a, cbv.x))));
        float upb = fmaf(cwb.w, u0b, fmaf(cwb.z, um1b, fmaf(cwb.y, um2b, fmaf(cwb.x, um3b, cbv.y))));
        um3a = um2a; um2a = um1a; um1a = u0a;
        um3b = um2b; um2b = um1b; um1b = u0b;
        #pragma unroll
        for (int n = 0; n < DSTATE; n++) {
            float dA = sdA[hh][t][n], dB = sdB[hh][t][n];
            ha[n] = fmaf(ha[n], dA, upa * dB);
            hb[n] = fmaf(hb[n], dA, upb * dB);
        }
    }
    float4* hl = (float4*)(hloc + (((size_t)c * NH + h) * PH + li * 2) * DSTATE);
    #pragma unroll
    for (int q = 0; q < 4; q++) hl[q]     = make_float4(ha[q*4], ha[q*4+1], ha[q*4+2], ha[q*4+3]);
    #pragma unroll
    for (int q = 0; q < 4; q++) hl[4 + q] = make_float4(hb[q*4], hb[q*4+1], hb[q*4+2], hb[q*4+3]);

    if (pidx < 32) {
        int hh4 = pidx >> 4, n = pidx & 15;
        float pr = 1.f;
        for (int t = 0; t < LC; t++) pr *= sdA[hh4][t][n];
        Pc[((size_t)c * NH + hp * 2 + hh4) * DSTATE + n] = pr;
    }
}

// ---------------- scan phase 2: serial carry across chunks (per batch) ----------------
__global__ __launch_bounds__(256) void scan_carry(const float* __restrict__ hloc,
                                                  const float* __restrict__ Pc,
                                                  float* __restrict__ Hent) {
    int g = blockIdx.x * 256 + threadIdx.x;
    int b = g >> 15;
    int r = g & 32767;
    int h = r >> 12;
    int inner = r & 4095;
    int n = r & 15;
    float carry = 0.f;
    for (int i = 0; i < NCB; i++) {
        int c = b * NCB + i;
        size_t idx = ((size_t)c * NH + h) * (PH * DSTATE) + inner;
        Hent[idx] = carry;
        carry = fmaf(Pc[((size_t)c * NH + h) * DSTATE + n], carry, hloc[idx]);
    }
}

// ---------------- scan phase 3: 2 channels/thread; gate + residual + ssq partials ----------------
__global__ __launch_bounds__(256) void scan_out(const ushort* __restrict__ Zb,
                                                const ushort* __restrict__ Ub,
                                                const ushort* __restrict__ RESb,
                                                ushort* __restrict__ Yb,
                                                float* __restrict__ ssqp,
                                                const float* __restrict__ DBC,
                                                const float* __restrict__ W_dt,
                                                const float* __restrict__ dt_bias,
                                                const float* __restrict__ A_log,
                                                const float* __restrict__ cw,
                                                const float* __restrict__ cb,
                                                const float* __restrict__ Dskip,
                                                const float* __restrict__ Hent) {
    const int c = blockIdx.x, hp = blockIdx.y;
    const int pidx = threadIdx.x;
    const int hh = pidx >> 7;
    const int h  = hp * 2 + hh;
    const int li = pidx & 127;
    const int ch = h * PH + li * 2;
    const int t0 = c * LC;
    const int wv = pidx >> 6, lane = pidx & 63;
    __shared__ float sdt[2][LC];
    __shared__ float sdA[2][LC][DSTATE];
    __shared__ float sdB[2][LC][DSTATE];
    __shared__ float sC [2][LC][DSTATE];
    __shared__ float sred[LC][4];

    if (pidx < 128) {
        const int hh2 = pidx >> 6, tt = pidx & 63;
        const int h2 = hp * 2 + hh2;
        const float* row = DBC + (size_t)(t0 + tt) * 320;
        const float* wd = W_dt + h2 * DTRANK;
        float acc = dt_bias[h2];
        #pragma unroll 16
        for (int r2 = 0; r2 < DTRANK; r2++) acc = fmaf(row[r2], wd[r2], acc);
        float sp = acc > 20.f ? acc : log1pf(expf(acc));
        sdt[hh2][tt] = fminf(fmaxf(sp, 1e-4f), 1.0f);
    }
    const float4 cwa = *(const float4*)(cw + ch * 4);
    const float4 cwb = *(const float4*)(cw + ch * 4 + 4);
    const float2 cbv = *(const float2*)(cb + ch);
    const float2 dskv = *(const float2*)(Dskip + ch);
    const int bs = (c / NCB) * MB_ROWS;
    float um3a = 0.f, um2a = 0.f, um1a = 0.f, um3b = 0.f, um2b = 0.f, um1b = 0.f;
    if (t0 - 3 >= bs) { ushort2 v = *(const ushort2*)(Ub + (size_t)(t0 - 3) * DINNER + ch); um3a = bf2f(v.x); um3b = bf2f(v.y); }
    if (t0 - 2 >= bs) { ushort2 v = *(const ushort2*)(Ub + (size_t)(t0 - 2) * DINNER + ch); um2a = bf2f(v.x); um2b = bf2f(v.y); }
    if (t0 - 1 >= bs) { ushort2 v = *(const ushort2*)(Ub + (size_t)(t0 - 1) * DINNER + ch); um1a = bf2f(v.x); um1b = bf2f(v.y); }
    __syncthreads();

    {
        const int sn = li & 15, stt = li >> 4;
        const float nA = -expf(A_log[h * DSTATE + sn]);
        #pragma unroll
        for (int j = 0; j < 8; j++) {
            int tt = stt + j * 8;
            size_t trow = (size_t)(t0 + tt);
            float dv = sdt[hh][tt];
            sdA[hh][tt][sn] = expf(dv * nA);
            sdB[hh][tt][sn] = dv * DBC[trow * 320 + 64 + h * DSTATE + sn];
            sC [hh][tt][sn] =      DBC[trow * 320 + 192 + h * DSTATE + sn];
        }
    }
    float ha[DSTATE], hb[DSTATE];
    {
        const float4* he = (const float4*)(Hent + (((size_t)c * NH + h) * PH + li * 2) * DSTATE);
        #pragma unroll
        for (int q = 0; q < 4; q++) {
            float4 v = he[q];
            ha[q*4] = v.x; ha[q*4+1] = v.y; ha[q*4+2] = v.z; ha[q*4+3] = v.w;
        }
        #pragma unroll
        for (int q = 0; q < 4; q++) {
            float4 v = he[4 + q];
            hb[q*4] = v.x; hb[q*4+1] = v.y; hb[q*4+2] = v.z; hb[q*4+3] = v.w;
        }
    }
    __syncthreads();

    for (int t = 0; t < LC; t++) {
        size_t off = (size_t)(t0 + t) * DINNER + ch;
        ushort2 uv = *(const ushort2*)(Ub + off);
        float u0a = bf2f(uv.x), u0b = bf2f(uv.y);
        float upa = fmaf(cwa.w, u0a, fmaf(cwa.z, um1a, fmaf(cwa.y, um2a, fmaf(cwa.x, um3a, cbv.x))));
        float upb = fmaf(cwb.w, u0b, fmaf(cwb.z, um1b, fmaf(cwb.y, um2b, fmaf(cwb.x, um3b, cbv.y))));
        um3a = um2a; um2a = um1a; um1a = u0a;
        um3b = um2b; um2b = um1b; um1b = u0b;
        float aa = 0.f, ab = 0.f;
        #pragma unroll
        for (int n = 0; n < DSTATE; n++) {
            float dA = sdA[hh][t][n], dB = sdB[hh][t][n], dC = sC[hh][t][n];
            ha[n] = fmaf(ha[n], dA, upa * dB);
            hb[n] = fmaf(hb[n], dA, upb * dB);
            aa = fmaf(ha[n], dC, aa);
            ab = fmaf(hb[n], dC, ab);
        }
        float ya = fmaf(dskv.x, upa, aa);
        float yb = fmaf(dskv.y, upb, ab);
        ushort2 zv2 = *(const ushort2*)(Zb + off);
        ushort2 rv2 = *(const ushort2*)(RESb + off);
        float za = bf2f(zv2.x), zb2 = bf2f(zv2.y);
        float sa = za / (1.f + expf(-za));
        float sb = zb2 / (1.f + expf(-zb2));
        float ga = fmaf(ya, sa, bf2f(rv2.x));
        float gb = fmaf(yb, sb, bf2f(rv2.y));
        *(unsigned*)(Yb + off) = cvt2bf(ga, gb);
        float ss = fmaf(gb, gb, ga * ga);
        #pragma unroll
        for (int o2 = 32; o2 > 0; o2 >>= 1) ss += __shfl_down(ss, o2);
        if (lane == 0) sred[t][wv] = ss;
    }
    __syncthreads();
    if (pidx < 128) {   // per-head partial: head hh5 = waves 2*hh5, 2*hh5+1
        int hh5 = pidx >> 6, rr = pidx & 63;
        float s = sred[rr][hh5 * 2] + sred[rr][hh5 * 2 + 1];
        ssqp[(size_t)(t0 + rr) * 8 + hp * 2 + hh5] = s;
    }
}

// ---------------- workspace layout ----------------
struct Lay {
    float *DBC, *PC, *HLOC, *HENT, *SSQP;
    ushort *YB, *ZB, *UB, *RESB, *XBF, *WB;
    size_t total;
};
static Lay mk_layout(char* base, int Mr) {
    size_t o = 0;
    auto take = [&](size_t bytes) { char* p = base + o; o = (o + bytes + 255) & ~(size_t)255; return p; };
    Lay l;
    l.YB   = (ushort*)take((size_t)Mr * 2048 * 2);
    l.DBC  = (float*) take((size_t)Mr * 320 * 4);
    l.PC   = (float*) take((size_t)(Mr / 64) * NH * DSTATE * 4);
    l.HLOC = (float*) take((size_t)Mr * 512 * 4);
    l.HENT = (float*) take((size_t)Mr * 512 * 4);
    l.SSQP = (float*) take((size_t)Mr * 8 * 4);
    l.ZB   = (ushort*)take((size_t)Mr * 2048 * 2);
    l.UB   = (ushort*)take((size_t)Mr * 2048 * 2);
    l.RESB = (ushort*)take((size_t)Mr * 2048 * 2);
    l.XBF  = (ushort*)take((size_t)8192 * 1024 * 2);
    l.WB   = (ushort*)take(((size_t)NTOT2 * 1024 + (size_t)1024 * 2048) * 2);
    l.total = o;
    return l;
}

extern "C" void kernel_launch(void* const* d_in, const int* in_sizes, int n_in,
                              void* d_out, int out_size, void* d_ws, size_t ws_size,
                              hipStream_t stream) {
    const float* x       = (const float*)d_in[0];
    const float* W_in    = (const float*)d_in[1];
    const float* W_dt    = (const float*)d_in[2];
    const float* conv_w  = (const float*)d_in[3];
    const float* conv_b  = (const float*)d_in[4];
    const float* A_log   = (const float*)d_in[5];
    const float* Dskip   = (const float*)d_in[6];
    const float* dt_bias = (const float*)d_in[7];
    const float* norm_w  = (const float*)d_in[8];
    const float* W_out   = (const float*)d_in[9];
    const float* W_res   = (const float*)d_in[10];
    float* out = (float*)d_out;

    Lay probe = mk_layout(nullptr, 2 * MB_ROWS);
    const bool fat = ws_size >= probe.total;
    const int Mr = fat ? 2 * MB_ROWS : MB_ROWS;
    const int npass = fat ? 1 : 2;
    const int nbc = fat ? 2 : 1;
    Lay l = mk_layout((char*)d_ws, Mr);

    ushort* wcat = l.WB;                                  // repacked [Z|U|RES|DBC] 6528 x 1024
    ushort* wotb = wcat + (size_t)NTOT2 * 1024;           // W_out*norm_w, 1024 x 2048

    {
        const size_t total_gran = ((size_t)NTOT2 * 1024 + (size_t)1024 * 2048 + (size_t)8192 * 1024) / 8;
        cvt_all<<<(int)(total_gran / 256), 256, 0, stream>>>(W_in, W_res, W_out, norm_w, x, l.WB, l.XBF);
    }

    for (int b = 0; b < npass; b++) {
        const ushort* xb = l.XBF + (size_t)b * MB_ROWS * DMODEL;
        float* outb = out + (size_t)b * MB_ROWS * DMODEL;

        // 1. fused in-proj + residual GEMM -> Zb | Ub | RESb | DBC   (Mr x 6528 x 1024)
        gemm_fused<<<51 * (Mr / 256), 512, 0, stream>>>(xb, wcat, l.ZB, l.UB, l.RESB, l.DBC, 51, DMODEL);
        // 2. chunk-parallel scan (2 ch/thread, head-pair blocks)
        scan_local<<<dim3(Mr / LC, NH / 2), 256, 0, stream>>>(l.UB, l.DBC, W_dt, dt_bias, A_log,
                                                              conv_w, conv_b, l.HLOC, l.PC);
        scan_carry<<<nbc * 128, 256, 0, stream>>>(l.HLOC, l.PC, l.HENT);
        scan_out<<<dim3(Mr / LC, NH / 2), 256, 0, stream>>>(l.ZB, l.UB, l.RESB, l.YB, l.SSQP, l.DBC,
                                                            W_dt, dt_bias, A_log,
                                                            conv_w, conv_b, Dskip, l.HENT);
        // 3. out-projection with fused rmsnorm: out = (Yb * inv_row) @ (W_out*norm_w)^T
        gemm_out128<<<8 * (Mr / 128), 256, 0, stream>>>(l.YB, wotb, l.SSQP, outb, 8, DINNER, DMODEL);
    }
}

// Round 16
// 297.182 us; speedup vs baseline: 1.0088x; 1.0088x over previous
//
#include <hip/hip_runtime.h>
#include <hip/hip_bf16.h>
#include <math.h>

#define DMODEL  1024
#define DINNER  2048
#define DSTATE  16
#define DCONV   4
#define DTRANK  64
#define NH      8
#define PH      256
#define TOTOUT  4416
#define NTOT2   6528            // [Z 2048 | U 2048 | RES 2048 | DBC 320+64pad] = 51*128
#define MB_ROWS 4096            // rows per batch
#define LC      64              // scan chunk length
#define NCB     (MB_ROWS/LC)    // 64 chunks per batch

typedef __attribute__((ext_vector_type(8))) short bf16x8;
typedef __attribute__((ext_vector_type(4))) float f32x4;

__device__ inline unsigned cvt2bf(float lo, float hi) {
    unsigned r;
    asm("v_cvt_pk_bf16_f32 %0, %1, %2" : "=v"(r) : "v"(lo), "v"(hi));
    return r;
}
__device__ inline ushort f2bf(float v) { return (ushort)(cvt2bf(v, v) & 0xffffu); }
__device__ inline float bf2f(ushort u) {
    union { unsigned u; float f; } w; w.u = (unsigned)u << 16; return w.f;
}
__device__ inline void gload16(const ushort* g, ushort* l) {
    __builtin_amdgcn_global_load_lds((const __attribute__((address_space(1))) unsigned*)(const void*)g,
                                     (__attribute__((address_space(3))) unsigned*)(void*)l, 16, 0, 0);
}

// ---------------- fused convert: Wcat repack [Wz|Wu|Wres|Wbc|pad] + W_out + x ----------------
__global__ __launch_bounds__(256) void cvt_all(const float* __restrict__ W_in,
                                               const float* __restrict__ W_res,
                                               const float* __restrict__ W_out,
                                               const float* __restrict__ x,
                                               ushort* __restrict__ WB,
                                               ushort* __restrict__ XBF) {
    const size_t E_WCAT = (size_t)NTOT2 * DMODEL;
    const size_t E_WOUT = E_WCAT + (size_t)DMODEL * DINNER;
    size_t i = ((size_t)blockIdx.x * 256 + threadIdx.x) * 8;
    const float* src;
    ushort* dst;
    bool zero = false;
    if (i < E_WCAT) {
        size_t r = i >> 10, c = i & 1023;
        if (r < 4096)       src = W_in + (r << 10) + c;           // z,u rows
        else if (r < 6144)  src = W_res + ((r - 4096) << 10) + c; // res rows
        else if (r < 6464)  src = W_in + ((r - 2048) << 10) + c;  // dbc rows 4096..4415
        else { src = W_in; zero = true; }                          // pad rows
        dst = WB + i;
    } else if (i < E_WOUT) {
        src = W_out + (i - E_WCAT);
        dst = WB + i;
    } else {
        src = x + (i - E_WOUT);
        dst = XBF + (i - E_WOUT);
    }
    float4 v0, v1;
    if (zero) { v0 = make_float4(0.f, 0.f, 0.f, 0.f); v1 = v0; }
    else { v0 = *(const float4*)src; v1 = *(const float4*)(src + 4); }
    uint4 o;
    o.x = cvt2bf(v0.x, v0.y); o.y = cvt2bf(v0.z, v0.w);
    o.z = cvt2bf(v1.x, v1.y); o.w = cvt2bf(v1.z, v1.w);
    *(uint4*)dst = o;
}

// ========== fused GEMM: 256x128 tile, tri-buffer, counted vmcnt(3) (round-10 proven) ==========
// C = A[Mr x 1024]bf16 x Wcat[6528 x 1024]^T, split epilogue Zb|Ub|RESb|DBC.
// 8 waves (4M x 2N), 64x64/wave, BK=32, 72 KB LDS -> 2 blocks/CU.
__global__ __launch_bounds__(512) void gemm_fused(const ushort* __restrict__ A,
                                                  const ushort* __restrict__ W,
                                                  ushort* __restrict__ Zb,
                                                  ushort* __restrict__ Ub,
                                                  ushort* __restrict__ RESb,
                                                  float* __restrict__ DBCp,
                                                  int ntx, int K) {
    __shared__ __align__(16) ushort L[3 * 12288];
    const int nwg  = gridDim.x;
    const int orig = blockIdx.x;
    const int swz  = (orig & 7) * (nwg >> 3) + (orig >> 3);   // bijective: nwg % 8 == 0
    const int bx = swz % ntx, by = swz / ntx;
    const int row0 = by * 256, col0 = bx * 128;

    const int t    = threadIdx.x;
    const int lane = t & 63, w = t >> 6;
    const int wr   = w >> 1, wc = w & 1;       // 4 M-waves x 2 N-waves
    const int l15  = lane & 15, l4 = lane >> 4;

    const int r0g = t >> 2, s0g = t & 3;
    const int r1g = r0g + 128;
    const int rr0 = r0g ^ ((r0g >> 3) & 1), cc0 = s0g ^ ((r0g >> 1) & 3);
    const int rr1 = r1g ^ ((r1g >> 3) & 1), cc1 = s0g ^ ((r1g >> 1) & 3);
    const ushort* sA0 = A + (size_t)(row0 + rr0) * K + cc0 * 8;
    const ushort* sA1 = A + (size_t)(row0 + rr1) * K + cc1 * 8;
    const ushort* sB0 = W + (size_t)(col0 + rr0) * K + cc0 * 8;

    int offA[4], offB[4];
    #pragma unroll
    for (int mi = 0; mi < 4; mi++) {
        int rq = wr * 64 + mi * 16 + l15;
        offA[mi] = (rq * 32 + l4 * 8) ^ (((rq >> 1) & 7) << 3);
    }
    #pragma unroll
    for (int ni = 0; ni < 4; ni++) {
        int rq = wc * 64 + ni * 16 + l15;
        offB[ni] = 8192 + ((rq * 32 + l4 * 8) ^ (((rq >> 1) & 7) << 3));
    }

    f32x4 acc[4][4];
    #pragma unroll
    for (int i = 0; i < 4; i++)
        #pragma unroll
        for (int j = 0; j < 4; j++)
            acc[i][j] = (f32x4){0.f, 0.f, 0.f, 0.f};

    const int KT = K >> 5;
    gload16(sA0,      &L[t * 8]);
    gload16(sA1,      &L[4096 + t * 8]);
    gload16(sB0,      &L[8192 + t * 8]);
    gload16(sA0 + 32, &L[12288 + t * 8]);
    gload16(sA1 + 32, &L[12288 + 4096 + t * 8]);
    gload16(sB0 + 32, &L[12288 + 8192 + t * 8]);
    asm volatile("s_waitcnt vmcnt(3)" ::: "memory");
    __builtin_amdgcn_sched_barrier(0);
    __builtin_amdgcn_s_barrier();
    __builtin_amdgcn_sched_barrier(0);

    for (int kt = 0; kt < KT; ++kt) {
        const bool pre = (kt + 2) < KT;
        if (pre) {
            ushort* bp2 = &L[((kt + 2) % 3) * 12288];
            const int ko = (kt + 2) << 5;
            gload16(sA0 + ko, bp2 + t * 8);
            gload16(sA1 + ko, bp2 + 4096 + t * 8);
            gload16(sB0 + ko, bp2 + 8192 + t * 8);
        }
        const ushort* bp = &L[(kt % 3) * 12288];
        bf16x8 af[4], bw[4];
        #pragma unroll
        for (int mi = 0; mi < 4; mi++) af[mi] = *(const bf16x8*)(bp + offA[mi]);
        #pragma unroll
        for (int ni = 0; ni < 4; ni++) bw[ni] = *(const bf16x8*)(bp + offB[ni]);
        __builtin_amdgcn_s_setprio(1);
        #pragma unroll
        for (int mi = 0; mi < 4; mi++)
            #pragma unroll
            for (int ni = 0; ni < 4; ni++)
                acc[mi][ni] = __builtin_amdgcn_mfma_f32_16x16x32_bf16(af[mi], bw[ni], acc[mi][ni], 0, 0, 0);
        __builtin_amdgcn_s_setprio(0);
        if (pre) { asm volatile("s_waitcnt vmcnt(3)" ::: "memory"); }
        else     { asm volatile("s_waitcnt vmcnt(0)" ::: "memory"); }
        __builtin_amdgcn_sched_barrier(0);
        __builtin_amdgcn_s_barrier();
        __builtin_amdgcn_sched_barrier(0);
    }

    // epilogue: C/D col=lane&15, row=(lane>>4)*4+reg [m89/m91]; split by col0 (block-uniform)
    #pragma unroll
    for (int mi = 0; mi < 4; mi++) {
        #pragma unroll
        for (int ni = 0; ni < 4; ni++) {
            #pragma unroll
            for (int rr = 0; rr < 4; rr++) {
                const int row = row0 + wr * 64 + mi * 16 + l4 * 4 + rr;
                const int col = col0 + wc * 64 + ni * 16 + l15;
                const float v = acc[mi][ni][rr];
                if (col0 < DINNER) {
                    Zb[(size_t)row * DINNER + col] = f2bf(v);
                } else if (col0 < 2 * DINNER) {
                    Ub[(size_t)row * DINNER + (col - DINNER)] = f2bf(v);
                } else if (col0 < 3 * DINNER) {
                    RESb[(size_t)row * DINNER + (col - 2 * DINNER)] = f2bf(v);
                } else {
                    if (col < 3 * DINNER + 320)
                        DBCp[(size_t)row * 320 + (col - 3 * DINNER)] = v;
                }
            }
        }
    }
}

// ========== out-proj GEMM: 128x128 tile, tri-buffer, counted vmcnt(4), fp32 out ==========
__global__ __launch_bounds__(256) void gemm_out128(const ushort* __restrict__ A,
                                                   const ushort* __restrict__ W,
                                                   float* __restrict__ C0,
                                                   int ntx, int K, int ldc) {
    __shared__ __align__(16) ushort L[3 * 8192];
    const int nwg  = gridDim.x;
    const int orig = blockIdx.x;
    const int swz  = (orig & 7) * (nwg >> 3) + (orig >> 3);
    const int bx = swz % ntx, by = swz / ntx;
    const int row0 = by * 128, col0 = bx * 128;

    const int t    = threadIdx.x;
    const int lane = t & 63, w = t >> 6;
    const int wr   = w >> 1, wc = w & 1;
    const int l15  = lane & 15, l4 = lane >> 4;

    const int r0g = t >> 2, s0g = t & 3;
    const int r1g = r0g + 64;
    const int rr0 = r0g ^ ((r0g >> 3) & 1), cc0 = s0g ^ ((r0g >> 1) & 3);
    const int rr1 = r1g ^ ((r1g >> 3) & 1), cc1 = s0g ^ ((r1g >> 1) & 3);
    const ushort* sA0 = A + (size_t)(row0 + rr0) * K + cc0 * 8;
    const ushort* sA1 = A + (size_t)(row0 + rr1) * K + cc1 * 8;
    const ushort* sB0 = W + (size_t)(col0 + rr0) * K + cc0 * 8;
    const ushort* sB1 = W + (size_t)(col0 + rr1) * K + cc1 * 8;

    int offA[4], offB[4];
    #pragma unroll
    for (int mi = 0; mi < 4; mi++) {
        int rq = wr * 64 + mi * 16 + l15;
        offA[mi] = (rq * 32 + l4 * 8) ^ (((rq >> 1) & 7) << 3);
    }
    #pragma unroll
    for (int ni = 0; ni < 4; ni++) {
        int rq = wc * 64 + ni * 16 + l15;
        offB[ni] = 4096 + ((rq * 32 + l4 * 8) ^ (((rq >> 1) & 7) << 3));
    }

    f32x4 acc[4][4];
    #pragma unroll
    for (int i = 0; i < 4; i++)
        #pragma unroll
        for (int j = 0; j < 4; j++)
            acc[i][j] = (f32x4){0.f, 0.f, 0.f, 0.f};

    const int KT = K >> 5;
    gload16(sA0,      &L[t * 8]);
    gload16(sA1,      &L[2048 + t * 8]);
    gload16(sB0,      &L[4096 + t * 8]);
    gload16(sB1,      &L[6144 + t * 8]);
    gload16(sA0 + 32, &L[8192 + t * 8]);
    gload16(sA1 + 32, &L[8192 + 2048 + t * 8]);
    gload16(sB0 + 32, &L[8192 + 4096 + t * 8]);
    gload16(sB1 + 32, &L[8192 + 6144 + t * 8]);
    asm volatile("s_waitcnt vmcnt(4)" ::: "memory");
    __builtin_amdgcn_sched_barrier(0);
    __builtin_amdgcn_s_barrier();
    __builtin_amdgcn_sched_barrier(0);

    for (int kt = 0; kt < KT; ++kt) {
        const bool pre = (kt + 2) < KT;
        if (pre) {
            ushort* bp2 = &L[((kt + 2) % 3) * 8192];
            const int ko = (kt + 2) << 5;
            gload16(sA0 + ko, bp2 + t * 8);
            gload16(sA1 + ko, bp2 + 2048 + t * 8);
            gload16(sB0 + ko, bp2 + 4096 + t * 8);
            gload16(sB1 + ko, bp2 + 6144 + t * 8);
        }
        const ushort* bp = &L[(kt % 3) * 8192];
        bf16x8 af[4], bw[4];
        #pragma unroll
        for (int mi = 0; mi < 4; mi++) af[mi] = *(const bf16x8*)(bp + offA[mi]);
        #pragma unroll
        for (int ni = 0; ni < 4; ni++) bw[ni] = *(const bf16x8*)(bp + offB[ni]);
        __builtin_amdgcn_s_setprio(1);
        #pragma unroll
        for (int mi = 0; mi < 4; mi++)
            #pragma unroll
            for (int ni = 0; ni < 4; ni++)
                acc[mi][ni] = __builtin_amdgcn_mfma_f32_16x16x32_bf16(af[mi], bw[ni], acc[mi][ni], 0, 0, 0);
        __builtin_amdgcn_s_setprio(0);
        if (pre) { asm volatile("s_waitcnt vmcnt(4)" ::: "memory"); }
        else     { asm volatile("s_waitcnt vmcnt(0)" ::: "memory"); }
        __builtin_amdgcn_sched_barrier(0);
        __builtin_amdgcn_s_barrier();
        __builtin_amdgcn_sched_barrier(0);
    }

    #pragma unroll
    for (int mi = 0; mi < 4; mi++)
        #pragma unroll
        for (int ni = 0; ni < 4; ni++)
            #pragma unroll
            for (int rr = 0; rr < 4; rr++) {
                const int row = row0 + wr * 64 + mi * 16 + l4 * 4 + rr;
                const int col = col0 + wc * 64 + ni * 16 + l15;
                C0[(size_t)row * ldc + col] = acc[mi][ni][rr];
            }
}

// ---------------- scan phase 1: inline dt + fused conv + per-chunk local end-state ----------------
__global__ __launch_bounds__(256) void scan_local(const ushort* __restrict__ Ub,
                                                  const float* __restrict__ DBC,
                                                  const float* __restrict__ W_dt,
                                                  const float* __restrict__ dt_bias,
                                                  const float* __restrict__ A_log,
                                                  const float* __restrict__ cw,
                                                  const float* __restrict__ cb,
                                                  float* __restrict__ hloc,
                                                  float* __restrict__ Pc) {
    const int c = blockIdx.x, h = blockIdx.y;
    const int pidx = threadIdx.x;
    const int ch = h * PH + pidx;
    const int t0 = c * LC;
    __shared__ float sdt[LC];
    __shared__ float sdA[LC][DSTATE];
    __shared__ float sdB[LC][DSTATE];
    const int st = pidx >> 4, sn = pidx & 15;

    if (pidx < LC) {   // dt head: dot64 + softplus + clip
        const float* row = DBC + (size_t)(t0 + pidx) * 320;
        const float* wd = W_dt + h * DTRANK;
        float acc = dt_bias[h];
        #pragma unroll 16
        for (int r2 = 0; r2 < DTRANK; r2++) acc = fmaf(row[r2], wd[r2], acc);
        float sp = acc > 20.f ? acc : log1pf(expf(acc));
        sdt[pidx] = fminf(fmaxf(sp, 1e-4f), 1.0f);
    }
    const float w0 = cw[ch * 4], w1 = cw[ch * 4 + 1], w2 = cw[ch * 4 + 2], w3 = cw[ch * 4 + 3];
    const float bia = cb[ch];
    const int bs = (c / NCB) * MB_ROWS;
    float um3 = (t0 - 3 >= bs) ? bf2f(Ub[(size_t)(t0 - 3) * DINNER + ch]) : 0.f;
    float um2 = (t0 - 2 >= bs) ? bf2f(Ub[(size_t)(t0 - 2) * DINNER + ch]) : 0.f;
    float um1 = (t0 - 1 >= bs) ? bf2f(Ub[(size_t)(t0 - 1) * DINNER + ch]) : 0.f;
    __syncthreads();

    {   // coefficient staging with inline dA = exp(dt * -exp(A_log))
        const float nA = -expf(A_log[h * DSTATE + sn]);
        #pragma unroll
        for (int j = 0; j < 4; j++) {
            int tt = st + j * 16;
            size_t trow = (size_t)(t0 + tt);
            float dv = sdt[tt];
            sdA[tt][sn] = expf(dv * nA);
            sdB[tt][sn] = dv * DBC[trow * 320 + 64 + h * DSTATE + sn];
        }
    }
    __syncthreads();

    float hst[DSTATE] = {};
    for (int t = 0; t < LC; t++) {
        float u0 = bf2f(Ub[(size_t)(t0 + t) * DINNER + ch]);
        float up = fmaf(w3, u0, fmaf(w2, um1, fmaf(w1, um2, fmaf(w0, um3, bia))));
        um3 = um2; um2 = um1; um1 = u0;
        #pragma unroll
        for (int n = 0; n < DSTATE; n++)
            hst[n] = fmaf(hst[n], sdA[t][n], up * sdB[t][n]);
    }
    float* hl = hloc + (((size_t)c * NH + h) * PH + pidx) * DSTATE;
    #pragma unroll
    for (int n = 0; n < DSTATE; n++) hl[n] = hst[n];

    if (pidx < DSTATE) {
        float pr = 1.f;
        for (int t = 0; t < LC; t++) pr *= sdA[t][pidx];
        Pc[((size_t)c * NH + h) * DSTATE + pidx] = pr;
    }
}

// ---------------- scan phase 2: serial carry across chunks (per batch) ----------------
__global__ __launch_bounds__(256) void scan_carry(const float* __restrict__ hloc,
                                                  const float* __restrict__ Pc,
                                                  float* __restrict__ Hent) {
    int g = blockIdx.x * 256 + threadIdx.x;
    int b = g >> 15;
    int r = g & 32767;
    int h = r >> 12;
    int inner = r & 4095;
    int n = r & 15;
    float carry = 0.f;
    for (int i = 0; i < NCB; i++) {
        int c = b * NCB + i;
        size_t idx = ((size_t)c * NH + h) * (PH * DSTATE) + inner;
        Hent[idx] = carry;
        carry = fmaf(Pc[((size_t)c * NH + h) * DSTATE + n], carry, hloc[idx]);
    }
}

// ---------------- scan phase 3: inline dt + conv + re-run chunk + skip + silu gate + residual ----------------
__global__ __launch_bounds__(256) void scan_out(const ushort* __restrict__ Zb,
                                                const ushort* __restrict__ Ub,
                                                const ushort* __restrict__ RESb,
                                                ushort* __restrict__ Yb,
                                                const float* __restrict__ DBC,
                                                const float* __restrict__ W_dt,
                                                const float* __restrict__ dt_bias,
                                                const float* __restrict__ A_log,
                                                const float* __restrict__ cw,
                                                const float* __restrict__ cb,
                                                const float* __restrict__ Dskip,
                                                const float* __restrict__ Hent) {
    const int c = blockIdx.x, h = blockIdx.y;
    const int pidx = threadIdx.x;
    const int ch = h * PH + pidx;
    const int t0 = c * LC;
    __shared__ float sdt[LC];
    __shared__ float sdA[LC][DSTATE];
    __shared__ float sdB[LC][DSTATE];
    __shared__ float sC [LC][DSTATE];
    const int st = pidx >> 4, sn = pidx & 15;

    if (pidx < LC) {
        const float* row = DBC + (size_t)(t0 + pidx) * 320;
        const float* wd = W_dt + h * DTRANK;
        float acc = dt_bias[h];
        #pragma unroll 16
        for (int r2 = 0; r2 < DTRANK; r2++) acc = fmaf(row[r2], wd[r2], acc);
        float sp = acc > 20.f ? acc : log1pf(expf(acc));
        sdt[pidx] = fminf(fmaxf(sp, 1e-4f), 1.0f);
    }
    const float w0 = cw[ch * 4], w1 = cw[ch * 4 + 1], w2 = cw[ch * 4 + 2], w3 = cw[ch * 4 + 3];
    const float bia = cb[ch];
    const int bs = (c / NCB) * MB_ROWS;
    float um3 = (t0 - 3 >= bs) ? bf2f(Ub[(size_t)(t0 - 3) * DINNER + ch]) : 0.f;
    float um2 = (t0 - 2 >= bs) ? bf2f(Ub[(size_t)(t0 - 2) * DINNER + ch]) : 0.f;
    float um1 = (t0 - 1 >= bs) ? bf2f(Ub[(size_t)(t0 - 1) * DINNER + ch]) : 0.f;
    __syncthreads();

    {
        const float nA = -expf(A_log[h * DSTATE + sn]);
        #pragma unroll
        for (int j = 0; j < 4; j++) {
            int tt = st + j * 16;
            size_t trow = (size_t)(t0 + tt);
            float dv = sdt[tt];
            sdA[tt][sn] = expf(dv * nA);
            sdB[tt][sn] = dv * DBC[trow * 320 + 64 + h * DSTATE + sn];
            sC [tt][sn] =      DBC[trow * 320 + 192 + h * DSTATE + sn];
        }
    }
    const float dsk = Dskip[ch];
    float hst[DSTATE];
    const float* he = Hent + (((size_t)c * NH + h) * PH + pidx) * DSTATE;
    #pragma unroll
    for (int n = 0; n < DSTATE; n++) hst[n] = he[n];
    __syncthreads();

    for (int t = 0; t < LC; t++) {
        size_t off = (size_t)(t0 + t) * DINNER + ch;
        float u0 = bf2f(Ub[off]);
        float up = fmaf(w3, u0, fmaf(w2, um1, fmaf(w1, um2, fmaf(w0, um3, bia))));
        um3 = um2; um2 = um1; um1 = u0;
        float a0 = 0.f, a1 = 0.f, a2 = 0.f, a3 = 0.f;
        #pragma unroll
        for (int n = 0; n < 4; n++) {
            hst[n +  0] = fmaf(hst[n +  0], sdA[t][n +  0], up * sdB[t][n +  0]);
            hst[n +  4] = fmaf(hst[n +  4], sdA[t][n +  4], up * sdB[t][n +  4]);
            hst[n +  8] = fmaf(hst[n +  8], sdA[t][n +  8], up * sdB[t][n +  8]);
            hst[n + 12] = fmaf(hst[n + 12], sdA[t][n + 12], up * sdB[t][n + 12]);
            a0 = fmaf(hst[n +  0], sC[t][n +  0], a0);
            a1 = fmaf(hst[n +  4], sC[t][n +  4], a1);
            a2 = fmaf(hst[n +  8], sC[t][n +  8], a2);
            a3 = fmaf(hst[n + 12], sC[t][n + 12], a3);
        }
        float yv = ((a0 + a1) + (a2 + a3)) + dsk * up;
        float zv = bf2f(Zb[off]);
        float sil = zv / (1.f + expf(-zv));
        Yb[off] = f2bf(fmaf(yv, sil, bf2f(RESb[off])));
    }
}

// ---------------- RMSNorm (bf16 in), bf16 output ----------------
__global__ __launch_bounds__(256) void rmsnorm_bf(const ushort* __restrict__ Yb,
                                                  const float* __restrict__ norm_w,
                                                  ushort* __restrict__ Gb) {
    const int row = blockIdx.x;
    const ushort* r = Yb + (size_t)row * DINNER;
    const int c0 = threadIdx.x * 8;
    uint4 packed = *(const uint4*)(r + c0);
    float v[8];
    v[0] = bf2f((ushort)(packed.x & 0xffff)); v[1] = bf2f((ushort)(packed.x >> 16));
    v[2] = bf2f((ushort)(packed.y & 0xffff)); v[3] = bf2f((ushort)(packed.y >> 16));
    v[4] = bf2f((ushort)(packed.z & 0xffff)); v[5] = bf2f((ushort)(packed.z >> 16));
    v[6] = bf2f((ushort)(packed.w & 0xffff)); v[7] = bf2f((ushort)(packed.w >> 16));
    float ss = 0.f;
    #pragma unroll
    for (int i = 0; i < 8; i++) ss = fmaf(v[i], v[i], ss);
    #pragma unroll
    for (int off = 32; off > 0; off >>= 1) ss += __shfl_down(ss, off);
    __shared__ float red[4];
    if ((threadIdx.x & 63) == 0) red[threadIdx.x >> 6] = ss;
    __syncthreads();
    float tot = red[0] + red[1] + red[2] + red[3];
    float inv = rsqrtf(tot / (float)DINNER + 1e-6f);
    float4 w0 = *(const float4*)(norm_w + c0);
    float4 w1 = *(const float4*)(norm_w + c0 + 4);
    uint4 o;
    o.x = cvt2bf(v[0] * inv * w0.x, v[1] * inv * w0.y);
    o.y = cvt2bf(v[2] * inv * w0.z, v[3] * inv * w0.w);
    o.z = cvt2bf(v[4] * inv * w1.x, v[5] * inv * w1.y);
    o.w = cvt2bf(v[6] * inv * w1.z, v[7] * inv * w1.w);
    *(uint4*)(Gb + (size_t)row * DINNER + c0) = o;
}

// ---------------- workspace layout ----------------
struct Lay {
    float *DBC, *PC, *HLOC, *HENT;
    ushort *YB, *ZB, *UB, *RESB, *XBF, *WB;
    size_t total;
};
static Lay mk_layout(char* base, int Mr) {
    size_t o = 0;
    auto take = [&](size_t bytes) { char* p = base + o; o = (o + bytes + 255) & ~(size_t)255; return p; };
    Lay l;
    l.YB   = (ushort*)take((size_t)Mr * 2048 * 2);
    l.DBC  = (float*) take((size_t)Mr * 320 * 4);
    l.PC   = (float*) take((size_t)(Mr / 64) * NH * DSTATE * 4);
    l.HLOC = (float*) take((size_t)Mr * 512 * 4);
    l.HENT = (float*) take((size_t)Mr * 512 * 4);
    l.ZB   = (ushort*)take((size_t)Mr * 2048 * 2);
    l.UB   = (ushort*)take((size_t)Mr * 2048 * 2);
    l.RESB = (ushort*)take((size_t)Mr * 2048 * 2);
    l.XBF  = (ushort*)take((size_t)8192 * 1024 * 2);
    l.WB   = (ushort*)take(((size_t)NTOT2 * 1024 + (size_t)1024 * 2048) * 2);
    l.total = o;
    return l;
}

extern "C" void kernel_launch(void* const* d_in, const int* in_sizes, int n_in,
                              void* d_out, int out_size, void* d_ws, size_t ws_size,
                              hipStream_t stream) {
    const float* x       = (const float*)d_in[0];
    const float* W_in    = (const float*)d_in[1];
    const float* W_dt    = (const float*)d_in[2];
    const float* conv_w  = (const float*)d_in[3];
    const float* conv_b  = (const float*)d_in[4];
    const float* A_log   = (const float*)d_in[5];
    const float* Dskip   = (const float*)d_in[6];
    const float* dt_bias = (const float*)d_in[7];
    const float* norm_w  = (const float*)d_in[8];
    const float* W_out   = (const float*)d_in[9];
    const float* W_res   = (const float*)d_in[10];
    float* out = (float*)d_out;

    Lay probe = mk_layout(nullptr, 2 * MB_ROWS);
    const bool fat = ws_size >= probe.total;
    const int Mr = fat ? 2 * MB_ROWS : MB_ROWS;
    const int npass = fat ? 1 : 2;
    const int nbc = fat ? 2 : 1;
    Lay l = mk_layout((char*)d_ws, Mr);

    ushort* wcat = l.WB;                                  // repacked [Z|U|RES|DBC] 6528 x 1024
    ushort* wotb = wcat + (size_t)NTOT2 * 1024;           // W_out 1024 x 2048
    ushort* Gb   = l.ZB;                                  // Z dead after scan_out; reuse for g

    // one fused conversion: weights (repacked) + W_out + x
    {
        const size_t total_gran = ((size_t)NTOT2 * 1024 + (size_t)1024 * 2048 + (size_t)8192 * 1024) / 8;
        cvt_all<<<(int)(total_gran / 256), 256, 0, stream>>>(W_in, W_res, W_out, x, l.WB, l.XBF);
    }

    for (int b = 0; b < npass; b++) {
        const ushort* xb = l.XBF + (size_t)b * MB_ROWS * DMODEL;
        float* outb = out + (size_t)b * MB_ROWS * DMODEL;

        // 1. fused in-proj + residual GEMM -> Zb | Ub | RESb | DBC   (Mr x 6528 x 1024)
        gemm_fused<<<51 * (Mr / 256), 512, 0, stream>>>(xb, wcat, l.ZB, l.UB, l.RESB, l.DBC, 51, DMODEL);
        // 2. chunk-parallel scan (inline dt, fused conv); y*silu(z)+res -> Yb (bf16)
        scan_local<<<dim3(Mr / LC, NH), 256, 0, stream>>>(l.UB, l.DBC, W_dt, dt_bias, A_log,
                                                          conv_w, conv_b, l.HLOC, l.PC);
        scan_carry<<<nbc * 128, 256, 0, stream>>>(l.HLOC, l.PC, l.HENT);
        scan_out<<<dim3(Mr / LC, NH), 256, 0, stream>>>(l.ZB, l.UB, l.RESB, l.YB, l.DBC,
                                                        W_dt, dt_bias, A_log,
                                                        conv_w, conv_b, Dskip, l.HENT);
        // 3. RMSNorm (bf16 in) -> bf16 g
        rmsnorm_bf<<<Mr, 256, 0, stream>>>(l.YB, norm_w, Gb);
        // 4. out-projection: out = g @ W_out^T (fp32 out), 128x128 tiles
        gemm_out128<<<8 * (Mr / 128), 256, 0, stream>>>(Gb, wotb, outb, 8, DINNER, DMODEL);
    }
}